// Round 3
// baseline (243.047 us; speedup 1.0000x reference)
//
#include <hip/hip_runtime.h>

// GlobalLocalPool: B=16, T=4096, H=512, fp32 in/out.
// out[b, 0:H]   = sum_{t < len[b]}  x[b,t,:] / max(len[b],1)
// out[b, H:2H]  = sum_{mask[b,t]}   x[b,t,:] / max(popcount(mask[b]),1)
// (span-compaction in the reference == plain masked mean; mask arrives as int32.)
//
// R2 lesson: conditional per-token loads serialize (1 outstanding load/wave,
// ~900 cy HBM latency) -> ~3x off BW roofline. This version loads every token
// unconditionally with predicate weights -> straight-line unrolled loads,
// full memory-level parallelism.

constexpr int Bc = 16;
constexpr int Tc = 4096;
constexpr int Hc = 512;
constexpr int CHUNK  = 64;          // tokens per block
constexpr int NCHUNK = Tc / CHUNK;  // 64 chunk-blocks per batch row

// Block = 256 threads: (tid&127) = float4 slice of H, (tid>>7) = token parity.
// Each thread streams 32 tokens with unconditional float4 loads.
__global__ __launch_bounds__(256) void glp_partial(
    const float* __restrict__ x,
    const int* __restrict__ lengths,
    const int* __restrict__ mask,   // int32 0/1
    float* __restrict__ gsum,       // [B][H]
    float* __restrict__ lsum,       // [B][H]
    int* __restrict__ cnt)          // [B]
{
    const int b    = blockIdx.x >> 6;          // / NCHUNK
    const int c    = blockIdx.x & (NCHUNK - 1);
    const int t0   = c * CHUNK;
    const int lane = threadIdx.x & 127;        // float4 index within H
    const int par  = threadIdx.x >> 7;         // token parity 0/1
    const int len  = lengths[b];

    const float4* __restrict__ xb =
        (const float4*)x + (size_t)b * Tc * (Hc / 4);
    const int* __restrict__ mb = mask + (size_t)b * Tc + t0;

    float4 g = make_float4(0.f, 0.f, 0.f, 0.f);
    float4 l = make_float4(0.f, 0.f, 0.f, 0.f);
    int mc = 0;

    #pragma unroll 8
    for (int i = 0; i < CHUNK / 2; ++i) {
        const int t = t0 + 2 * i + par;
        const float4 v = xb[(size_t)t * (Hc / 4) + lane];
        const int   m  = mb[2 * i + par];
        const float wg = (t < len) ? 1.f : 0.f;   // v_cndmask
        const float wl = m ? 1.f : 0.f;
        g.x = fmaf(v.x, wg, g.x); g.y = fmaf(v.y, wg, g.y);
        g.z = fmaf(v.z, wg, g.z); g.w = fmaf(v.w, wg, g.w);
        l.x = fmaf(v.x, wl, l.x); l.y = fmaf(v.y, wl, l.y);
        l.z = fmaf(v.z, wl, l.z); l.w = fmaf(v.w, wl, l.w);
        mc += (m != 0);
    }

    float* gp = gsum + b * Hc + lane * 4;
    float* lp = lsum + b * Hc + lane * 4;
    atomicAdd(gp + 0, g.x); atomicAdd(gp + 1, g.y);
    atomicAdd(gp + 2, g.z); atomicAdd(gp + 3, g.w);
    atomicAdd(lp + 0, l.x); atomicAdd(lp + 1, l.y);
    atomicAdd(lp + 2, l.z); atomicAdd(lp + 3, l.w);
    // Each parity's lane==0 thread holds that parity's exact masked-token count.
    if (lane == 0) atomicAdd(cnt + b, mc);
}

// Kernel 2: divide and emit [B, 2H].
__global__ __launch_bounds__(512) void glp_finalize(
    const float* __restrict__ gsum,
    const float* __restrict__ lsum,
    const int* __restrict__ cnt,
    const int* __restrict__ lengths,
    float* __restrict__ out)
{
    const int b = blockIdx.x;
    const int h = threadIdx.x;
    const float inv_len = 1.f / (float)max(lengths[b], 1);
    const float inv_cnt = 1.f / (float)max(cnt[b], 1);
    out[b * (2 * Hc) + h]      = gsum[b * Hc + h] * inv_len;
    out[b * (2 * Hc) + Hc + h] = lsum[b * Hc + h] * inv_cnt;
}

extern "C" void kernel_launch(void* const* d_in, const int* in_sizes, int n_in,
                              void* d_out, int out_size, void* d_ws, size_t ws_size,
                              hipStream_t stream) {
    const float* x     = (const float*)d_in[0];
    const int* lengths = (const int*)d_in[1];
    const int* mask    = (const int*)d_in[2];   // bool promoted to int32 by harness
    float* out = (float*)d_out;

    float* gsum = (float*)d_ws;
    float* lsum = gsum + Bc * Hc;
    int*   cnt  = (int*)(lsum + Bc * Hc);

    const size_t zero_bytes = (size_t)(2 * Bc * Hc) * sizeof(float) + Bc * sizeof(int);
    hipMemsetAsync(d_ws, 0, zero_bytes, stream);  // ws is poisoned 0xAA each call

    glp_partial<<<Bc * NCHUNK, 256, 0, stream>>>(x, lengths, mask, gsum, lsum, cnt);
    glp_finalize<<<Bc, Hc, 0, stream>>>(gsum, lsum, cnt, lengths, out);
}

// Round 4
// 199.395 us; speedup vs baseline: 1.2189x; 1.2189x over previous
//
#include <hip/hip_runtime.h>

// GlobalLocalPool: B=16, T=4096, H=512, fp32 in/out.
// out[b, 0:H]   = sum_{t < len[b]}  x[b,t,:] / max(len[b],1)
// out[b, H:2H]  = sum_{mask[b,t]}   x[b,t,:] / max(popcount(mask[b]),1)
// (span-compaction in the reference == plain masked mean; mask arrives as int32.)
//
// R3 lesson: per-iteration load->use chains left ~2 loads in flight/wave
// (VGPR=36, 1.01 TB/s, latency-bound). Fix: explicit 8-wide register batches
// (8 KB in flight per wave) + replace 2M float atomics (32.8 MB HBM write-
// through!) with per-block partials + a tiny reduce kernel.

constexpr int Bc = 16;
constexpr int Tc = 4096;
constexpr int Hc = 512;
constexpr int CHUNK  = 64;           // tokens per block
constexpr int NCHUNK = Tc / CHUNK;   // 64 chunks per batch row
constexpr int NBLK   = Bc * NCHUNK;  // 1024 stage-1 blocks

// ---------------- main path: partials, no atomics ----------------

// Block = 128 threads (2 waves); thread tid owns float4 column tid of H
// (H = 512 floats = 128 float4). Each thread streams all 64 tokens of its
// chunk in batches of 8 unconditional float4 loads.
__global__ __launch_bounds__(128) void glp_partial(
    const float* __restrict__ x,
    const int* __restrict__ lengths,
    const int* __restrict__ mask,   // int32 0/1
    float* __restrict__ pg,         // [NBLK][Hc] partial global sums
    float* __restrict__ pl,         // [NBLK][Hc] partial local sums
    int*   __restrict__ pcnt)       // [NBLK]     partial mask counts
{
    const int blk  = blockIdx.x;
    const int b    = blk >> 6;               // / NCHUNK
    const int c    = blk & (NCHUNK - 1);
    const int t0   = c * CHUNK;
    const int lane = threadIdx.x;            // 0..127 float4 column
    const int len  = lengths[b];

    const float4* __restrict__ xb =
        (const float4*)x + ((size_t)b * Tc + t0) * (Hc / 4) + lane;
    const int* __restrict__ mb = mask + (size_t)b * Tc + t0;  // wave-uniform addr

    float4 g = make_float4(0.f, 0.f, 0.f, 0.f);
    float4 l = make_float4(0.f, 0.f, 0.f, 0.f);
    int mc = 0;

    for (int ii = 0; ii < CHUNK; ii += 8) {
        float4 v[8];
        int    m[8];
        #pragma unroll
        for (int j = 0; j < 8; ++j) {        // 8 independent 16B loads back-to-back
            v[j] = xb[(size_t)(ii + j) * (Hc / 4)];
            m[j] = mb[ii + j];               // uniform -> scalar load (lgkmcnt)
        }
        #pragma unroll
        for (int j = 0; j < 8; ++j) {
            const float wg = (t0 + ii + j < len) ? 1.f : 0.f;
            const float wl = m[j] ? 1.f : 0.f;
            g.x = fmaf(v[j].x, wg, g.x); g.y = fmaf(v[j].y, wg, g.y);
            g.z = fmaf(v[j].z, wg, g.z); g.w = fmaf(v[j].w, wg, g.w);
            l.x = fmaf(v[j].x, wl, l.x); l.y = fmaf(v[j].y, wl, l.y);
            l.z = fmaf(v[j].z, wl, l.z); l.w = fmaf(v[j].w, wl, l.w);
            mc += (m[j] != 0);
        }
    }

    ((float4*)(pg + (size_t)blk * Hc))[lane] = g;   // coalesced 2 KB store
    ((float4*)(pl + (size_t)blk * Hc))[lane] = l;
    if (lane == 0) pcnt[blk] = mc;                  // mask uniform across lanes
}

// Stage 2: one block per b; reduce 64 partials per (b,h), divide, emit [B,2H].
__global__ __launch_bounds__(512) void glp_reduce(
    const float* __restrict__ pg,
    const float* __restrict__ pl,
    const int* __restrict__ pcnt,
    const int* __restrict__ lengths,
    float* __restrict__ out)
{
    const int b = blockIdx.x;
    const int h = threadIdx.x;
    const float* pgb = pg + (size_t)b * NCHUNK * Hc + h;
    const float* plb = pl + (size_t)b * NCHUNK * Hc + h;
    float gs = 0.f, ls = 0.f;
    #pragma unroll 8
    for (int c = 0; c < NCHUNK; ++c) {
        gs += pgb[(size_t)c * Hc];
        ls += plb[(size_t)c * Hc];
    }
    int cntv = 0;
    for (int c = 0; c < NCHUNK; ++c) cntv += pcnt[b * NCHUNK + c];  // uniform s_loads
    out[b * 2 * Hc + h]      = gs / (float)max(lengths[b], 1);
    out[b * 2 * Hc + Hc + h] = ls / (float)max(cntv, 1);
}

// ---------------- fallback path (ws too small): R2's proven atomic version ----

__global__ __launch_bounds__(128) void glp_partial_atomic(
    const float* __restrict__ x,
    const int* __restrict__ lengths,
    const int* __restrict__ mask,
    float* __restrict__ gsum, float* __restrict__ lsum, int* __restrict__ cnt)
{
    const int blk  = blockIdx.x;
    const int b    = blk >> 6;
    const int c    = blk & (NCHUNK - 1);
    const int t0   = c * CHUNK;
    const int lane = threadIdx.x;
    const int len  = lengths[b];
    const float4* __restrict__ xb =
        (const float4*)x + ((size_t)b * Tc + t0) * (Hc / 4) + lane;
    const int* __restrict__ mb = mask + (size_t)b * Tc + t0;

    float4 g = make_float4(0.f, 0.f, 0.f, 0.f);
    float4 l = make_float4(0.f, 0.f, 0.f, 0.f);
    int mc = 0;
    for (int ii = 0; ii < CHUNK; ii += 8) {
        float4 v[8]; int m[8];
        #pragma unroll
        for (int j = 0; j < 8; ++j) { v[j] = xb[(size_t)(ii + j) * (Hc / 4)]; m[j] = mb[ii + j]; }
        #pragma unroll
        for (int j = 0; j < 8; ++j) {
            const float wg = (t0 + ii + j < len) ? 1.f : 0.f;
            const float wl = m[j] ? 1.f : 0.f;
            g.x = fmaf(v[j].x, wg, g.x); g.y = fmaf(v[j].y, wg, g.y);
            g.z = fmaf(v[j].z, wg, g.z); g.w = fmaf(v[j].w, wg, g.w);
            l.x = fmaf(v[j].x, wl, l.x); l.y = fmaf(v[j].y, wl, l.y);
            l.z = fmaf(v[j].z, wl, l.z); l.w = fmaf(v[j].w, wl, l.w);
            mc += (m[j] != 0);
        }
    }
    float* gp = gsum + b * Hc + lane * 4;
    float* lp = lsum + b * Hc + lane * 4;
    atomicAdd(gp + 0, g.x); atomicAdd(gp + 1, g.y);
    atomicAdd(gp + 2, g.z); atomicAdd(gp + 3, g.w);
    atomicAdd(lp + 0, l.x); atomicAdd(lp + 1, l.y);
    atomicAdd(lp + 2, l.z); atomicAdd(lp + 3, l.w);
    if (lane == 0) atomicAdd(cnt + b, mc);
}

__global__ __launch_bounds__(512) void glp_finalize(
    const float* __restrict__ gsum, const float* __restrict__ lsum,
    const int* __restrict__ cnt, const int* __restrict__ lengths,
    float* __restrict__ out)
{
    const int b = blockIdx.x;
    const int h = threadIdx.x;
    out[b * 2 * Hc + h]      = gsum[b * Hc + h] / (float)max(lengths[b], 1);
    out[b * 2 * Hc + Hc + h] = lsum[b * Hc + h] / (float)max(cnt[b], 1);
}

extern "C" void kernel_launch(void* const* d_in, const int* in_sizes, int n_in,
                              void* d_out, int out_size, void* d_ws, size_t ws_size,
                              hipStream_t stream) {
    const float* x     = (const float*)d_in[0];
    const int* lengths = (const int*)d_in[1];
    const int* mask    = (const int*)d_in[2];   // bool promoted to int32 by harness
    float* out = (float*)d_out;

    const size_t need = (size_t)NBLK * Hc * sizeof(float) * 2 + NBLK * sizeof(int);
    if (ws_size >= need) {
        float* pg  = (float*)d_ws;
        float* pl  = pg + (size_t)NBLK * Hc;
        int* pcnt  = (int*)(pl + (size_t)NBLK * Hc);
        glp_partial<<<NBLK, 128, 0, stream>>>(x, lengths, mask, pg, pl, pcnt);
        glp_reduce<<<Bc, Hc, 0, stream>>>(pg, pl, pcnt, lengths, out);
    } else {
        float* gsum = (float*)d_ws;
        float* lsum = gsum + Bc * Hc;
        int*   cnt  = (int*)(lsum + Bc * Hc);
        const size_t zb = (size_t)(2 * Bc * Hc) * sizeof(float) + Bc * sizeof(int);
        hipMemsetAsync(d_ws, 0, zb, stream);
        glp_partial_atomic<<<NBLK, 128, 0, stream>>>(x, lengths, mask, gsum, lsum, cnt);
        glp_finalize<<<Bc, Hc, 0, stream>>>(gsum, lsum, cnt, lengths, out);
    }
}